// Round 1
// baseline (271.107 us; speedup 1.0000x reference)
//
#include <hip/hip_runtime.h>

// Problem constants (from reference): B=256, NSEL=60000, NVERTS=100000, F=3
#define B_C     256
#define NSEL_C  60000
#define NV_C    100000
#define SCAN_T  1024
#define NB1     ((NV_C + SCAN_T - 1) / SCAN_T)   // 98 scan blocks

// ---------------- CSR build ----------------

__global__ void zero_counts_k(int* __restrict__ counts) {
    int i = blockIdx.x * blockDim.x + threadIdx.x;
    if (i < NV_C) counts[i] = 0;
}

__global__ void hist_k(const int* __restrict__ vs, int* __restrict__ counts) {
    int j = blockIdx.x * blockDim.x + threadIdx.x;
    if (j < NSEL_C) atomicAdd(&counts[vs[j]], 1);
}

// Per-block inclusive scan (Hillis-Steele, 1024 wide); writes exclusive
// partials and per-block totals.
__global__ __launch_bounds__(SCAN_T) void scan1_k(const int* __restrict__ counts,
                                                  int* __restrict__ partial,
                                                  int* __restrict__ blockSums) {
    __shared__ int sm[SCAN_T];
    int tid = threadIdx.x;
    int i = blockIdx.x * SCAN_T + tid;
    int v = (i < NV_C) ? counts[i] : 0;
    int val = v;
    sm[tid] = val;
    __syncthreads();
    for (int off = 1; off < SCAN_T; off <<= 1) {
        int t = (tid >= off) ? sm[tid - off] : 0;
        __syncthreads();
        val += t;
        sm[tid] = val;
        __syncthreads();
    }
    if (i < NV_C) partial[i] = val - v;           // exclusive
    if (tid == SCAN_T - 1) blockSums[blockIdx.x] = val;
}

// 98 elements: serial scan by a single thread is microseconds.
__global__ void scan2_k(const int* __restrict__ blockSums, int* __restrict__ blockOff) {
    if (blockIdx.x == 0 && threadIdx.x == 0) {
        int run = 0;
        for (int b = 0; b < NB1; ++b) { blockOff[b] = run; run += blockSums[b]; }
    }
}

__global__ void scan3_k(const int* __restrict__ partial, const int* __restrict__ blockOff,
                        int* __restrict__ offsets, int* __restrict__ cursor) {
    int i = blockIdx.x * blockDim.x + threadIdx.x;
    if (i < NV_C) {
        int o = partial[i] + blockOff[i / SCAN_T];
        offsets[i] = o;
        cursor[i]  = o;
    }
    if (i == 0) offsets[NV_C] = NSEL_C;  // total count is known statically
}

__global__ void fill_k(const int* __restrict__ vs, int* __restrict__ cursor,
                       int* __restrict__ list) {
    int j = blockIdx.x * blockDim.x + threadIdx.x;
    if (j < NSEL_C) {
        int v = vs[j];
        int pos = atomicAdd(&cursor[v], 1);
        list[pos] = j;
    }
}

// ---------------- gather (the heavy kernel) ----------------
// One thread per (b, v): sum the ≤few contributing x rows, write out once.
// Consecutive threads -> consecutive v -> coalesced 12B/lane output stores.
// blockIdx.y = batch; per-batch x slice (720 KB) stays L2-resident.
__global__ __launch_bounds__(256) void gather_k(const float* __restrict__ x,
                                                const int* __restrict__ offsets,
                                                const int* __restrict__ list,
                                                float* __restrict__ out) {
    int v = blockIdx.x * 256 + threadIdx.x;
    int b = blockIdx.y;
    if (v >= NV_C) return;
    int s = offsets[v];
    int e = offsets[v + 1];
    const float* xb = x + (size_t)b * (NSEL_C * 3);
    float f0 = 0.f, f1 = 0.f, f2 = 0.f;
    for (int k = s; k < e; ++k) {
        int j = list[k];
        const float* p = xb + 3 * (size_t)j;
        f0 += p[0];
        f1 += p[1];
        f2 += p[2];
    }
    size_t o = ((size_t)b * NV_C + v) * 3;
    out[o + 0] = f0;
    out[o + 1] = f1;
    out[o + 2] = f2;
}

// ---------------- fallback (if ws too small): memset + atomic scatter ----------------
__global__ __launch_bounds__(256) void scatter_atomic_k(const float* __restrict__ x,
                                                        const int* __restrict__ vs,
                                                        float* __restrict__ out) {
    int j = blockIdx.x * blockDim.x + threadIdx.x;
    int b = blockIdx.y;
    if (j < NSEL_C) {
        int v = vs[j];
        const float* p = x + ((size_t)b * NSEL_C + j) * 3;
        float* q = out + ((size_t)b * NV_C + v) * 3;
        atomicAdd(q + 0, p[0]);
        atomicAdd(q + 1, p[1]);
        atomicAdd(q + 2, p[2]);
    }
}

extern "C" void kernel_launch(void* const* d_in, const int* in_sizes, int n_in,
                              void* d_out, int out_size, void* d_ws, size_t ws_size,
                              hipStream_t stream) {
    const float* x  = (const float*)d_in[0];
    const int*   vs = (const int*)d_in[1];
    float* out = (float*)d_out;

    // ws layout (ints): counts[NV] | partial[NV] | offsets[NV+1] | cursor[NV]
    //                   | blockSums[NB1] | blockOff[NB1] | list[NSEL]
    const size_t need_ints = (size_t)4 * NV_C + 1 + 2 * NB1 + NSEL_C;
    if (ws_size >= need_ints * sizeof(int)) {
        int* w        = (int*)d_ws;
        int* counts   = w;
        int* partial  = w + NV_C;
        int* offsets  = w + 2 * NV_C;          // NV_C + 1 entries
        int* cursor   = w + 3 * NV_C + 1;
        int* blockSums= w + 4 * NV_C + 1;
        int* blockOff = blockSums + NB1;
        int* list     = blockOff + NB1;

        zero_counts_k<<<(NV_C + 255) / 256, 256, 0, stream>>>(counts);
        hist_k<<<(NSEL_C + 255) / 256, 256, 0, stream>>>(vs, counts);
        scan1_k<<<NB1, SCAN_T, 0, stream>>>(counts, partial, blockSums);
        scan2_k<<<1, 64, 0, stream>>>(blockSums, blockOff);
        scan3_k<<<(NV_C + 255) / 256, 256, 0, stream>>>(partial, blockOff, offsets, cursor);
        fill_k<<<(NSEL_C + 255) / 256, 256, 0, stream>>>(vs, cursor, list);

        dim3 grid((NV_C + 255) / 256, B_C);
        gather_k<<<grid, 256, 0, stream>>>(x, offsets, list, out);
    } else {
        hipMemsetAsync(d_out, 0, (size_t)out_size * sizeof(float), stream);
        dim3 grid((NSEL_C + 255) / 256, B_C);
        scatter_atomic_k<<<grid, 256, 0, stream>>>(x, vs, out);
    }
}

// Round 2
// 207.901 us; speedup vs baseline: 1.3040x; 1.3040x over previous
//
#include <hip/hip_runtime.h>

// Problem constants (from reference): B=256, NSEL=60000, NVERTS=100000, F=3
#define B_C     256
#define NSEL_C  60000
#define NV_C    100000
#define SCAN_T  1024
#define NB1     ((NV_C + SCAN_T - 1) / SCAN_T)   // 98 scan blocks
#define NBLK_V  ((NV_C + 255) / 256)             // 391 vertex-blocks per batch
#define NXCD    8

// ---------------- CSR build ----------------

__global__ void zero_counts_k(int* __restrict__ counts) {
    int i = blockIdx.x * blockDim.x + threadIdx.x;
    if (i < NV_C) counts[i] = 0;
}

__global__ void hist_k(const int* __restrict__ vs, int* __restrict__ counts) {
    int j = blockIdx.x * blockDim.x + threadIdx.x;
    if (j < NSEL_C) atomicAdd(&counts[vs[j]], 1);
}

// Per-block inclusive scan (Hillis-Steele, 1024 wide); writes exclusive
// partials and per-block totals.
__global__ __launch_bounds__(SCAN_T) void scan1_k(const int* __restrict__ counts,
                                                  int* __restrict__ partial,
                                                  int* __restrict__ blockSums) {
    __shared__ int sm[SCAN_T];
    int tid = threadIdx.x;
    int i = blockIdx.x * SCAN_T + tid;
    int v = (i < NV_C) ? counts[i] : 0;
    int val = v;
    sm[tid] = val;
    __syncthreads();
    for (int off = 1; off < SCAN_T; off <<= 1) {
        int t = (tid >= off) ? sm[tid - off] : 0;
        __syncthreads();
        val += t;
        sm[tid] = val;
        __syncthreads();
    }
    if (i < NV_C) partial[i] = val - v;           // exclusive
    if (tid == SCAN_T - 1) blockSums[blockIdx.x] = val;
}

// 98 elements: serial scan by a single thread is microseconds.
__global__ void scan2_k(const int* __restrict__ blockSums, int* __restrict__ blockOff) {
    if (blockIdx.x == 0 && threadIdx.x == 0) {
        int run = 0;
        for (int b = 0; b < NB1; ++b) { blockOff[b] = run; run += blockSums[b]; }
    }
}

__global__ void scan3_k(const int* __restrict__ partial, const int* __restrict__ blockOff,
                        int* __restrict__ offsets, int* __restrict__ cursor) {
    int i = blockIdx.x * blockDim.x + threadIdx.x;
    if (i < NV_C) {
        int o = partial[i] + blockOff[i / SCAN_T];
        offsets[i] = o;
        cursor[i]  = o;
    }
    if (i == 0) offsets[NV_C] = NSEL_C;  // total count is known statically
}

__global__ void fill_k(const int* __restrict__ vs, int* __restrict__ cursor,
                       int* __restrict__ list) {
    int j = blockIdx.x * blockDim.x + threadIdx.x;
    if (j < NSEL_C) {
        int v = vs[j];
        int pos = atomicAdd(&cursor[v], 1);
        list[pos] = j;
    }
}

// ---------------- gather (the heavy kernel) ----------------
// One thread per (b, v): sum the ≤few contributing x rows, write out once.
// XCD-pinning swizzle: HW round-robins wg id across the 8 XCDs (xcd = id%8),
// so batch b gets only ids with id%8 == b%8 -> all 391 blocks of a batch land
// on ONE XCD and its 720 KB x-slice is fetched into that XCD's L2 exactly
// once. offsets/list (~640 KB) also stay L2-resident across that XCD's 32
// batches. Bijection: id = ((b/8)*NBLK_V + t)*8 + (b%8).
__global__ __launch_bounds__(256) void gather_k(const float* __restrict__ x,
                                                const int* __restrict__ offsets,
                                                const int* __restrict__ list,
                                                float* __restrict__ out) {
    int lin  = blockIdx.x;
    int xcd  = lin & (NXCD - 1);
    int rest = lin >> 3;                 // (b/8)*NBLK_V + t
    int t    = rest % NBLK_V;
    int b    = (rest / NBLK_V) * NXCD + xcd;

    int v = t * 256 + threadIdx.x;
    if (v >= NV_C) return;
    int s = offsets[v];
    int e = offsets[v + 1];
    const float* xb = x + (size_t)b * (NSEL_C * 3);
    float f0 = 0.f, f1 = 0.f, f2 = 0.f;
    for (int k = s; k < e; ++k) {
        int j = list[k];
        const float* p = xb + 3 * (size_t)j;
        f0 += p[0];
        f1 += p[1];
        f2 += p[2];
    }
    size_t o = ((size_t)b * NV_C + v) * 3;
    out[o + 0] = f0;
    out[o + 1] = f1;
    out[o + 2] = f2;
}

// ---------------- fallback (if ws too small): memset + atomic scatter ----------------
__global__ __launch_bounds__(256) void scatter_atomic_k(const float* __restrict__ x,
                                                        const int* __restrict__ vs,
                                                        float* __restrict__ out) {
    int j = blockIdx.x * blockDim.x + threadIdx.x;
    int b = blockIdx.y;
    if (j < NSEL_C) {
        int v = vs[j];
        const float* p = x + ((size_t)b * NSEL_C + j) * 3;
        float* q = out + ((size_t)b * NV_C + v) * 3;
        atomicAdd(q + 0, p[0]);
        atomicAdd(q + 1, p[1]);
        atomicAdd(q + 2, p[2]);
    }
}

extern "C" void kernel_launch(void* const* d_in, const int* in_sizes, int n_in,
                              void* d_out, int out_size, void* d_ws, size_t ws_size,
                              hipStream_t stream) {
    const float* x  = (const float*)d_in[0];
    const int*   vs = (const int*)d_in[1];
    float* out = (float*)d_out;

    // ws layout (ints): counts[NV] | partial[NV] | offsets[NV+1] | cursor[NV]
    //                   | blockSums[NB1] | blockOff[NB1] | list[NSEL]
    const size_t need_ints = (size_t)4 * NV_C + 1 + 2 * NB1 + NSEL_C;
    if (ws_size >= need_ints * sizeof(int)) {
        int* w        = (int*)d_ws;
        int* counts   = w;
        int* partial  = w + NV_C;
        int* offsets  = w + 2 * NV_C;          // NV_C + 1 entries
        int* cursor   = w + 3 * NV_C + 1;
        int* blockSums= w + 4 * NV_C + 1;
        int* blockOff = blockSums + NB1;
        int* list     = blockOff + NB1;

        zero_counts_k<<<(NV_C + 255) / 256, 256, 0, stream>>>(counts);
        hist_k<<<(NSEL_C + 255) / 256, 256, 0, stream>>>(vs, counts);
        scan1_k<<<NB1, SCAN_T, 0, stream>>>(counts, partial, blockSums);
        scan2_k<<<1, 64, 0, stream>>>(blockSums, blockOff);
        scan3_k<<<(NV_C + 255) / 256, 256, 0, stream>>>(partial, blockOff, offsets, cursor);
        fill_k<<<(NSEL_C + 255) / 256, 256, 0, stream>>>(vs, cursor, list);

        // 1-D swizzled grid: 256 batches x 391 vertex-blocks (100096 % 8 == 0)
        gather_k<<<B_C * NBLK_V, 256, 0, stream>>>(x, offsets, list, out);
    } else {
        hipMemsetAsync(d_out, 0, (size_t)out_size * sizeof(float), stream);
        dim3 grid((NSEL_C + 255) / 256, B_C);
        scatter_atomic_k<<<grid, 256, 0, stream>>>(x, vs, out);
    }
}

// Round 3
// 162.816 us; speedup vs baseline: 1.6651x; 1.2769x over previous
//
#include <hip/hip_runtime.h>

// Problem constants (from reference): B=256, NSEL=60000, NVERTS=100000, F=3
#define B_C     256
#define NSEL_C  60000
#define NV_C    100000
#define SCAN_T  1024
#define NB1     ((NV_C + SCAN_T - 1) / SCAN_T)   // 98 scan blocks
#define NGRP    (NV_C / 4)                       // 25000 groups of 4 vertices
#define NBLK_G  ((NGRP + 255) / 256)             // 98 group-blocks per batch
#define NXCD    8

typedef float f32x4 __attribute__((ext_vector_type(4)));

// ---------------- CSR build ----------------

__global__ void zero_counts_k(int* __restrict__ counts) {
    int i = blockIdx.x * blockDim.x + threadIdx.x;
    if (i < NV_C) counts[i] = 0;
}

__global__ void hist_k(const int* __restrict__ vs, int* __restrict__ counts) {
    int j = blockIdx.x * blockDim.x + threadIdx.x;
    if (j < NSEL_C) atomicAdd(&counts[vs[j]], 1);
}

__global__ __launch_bounds__(SCAN_T) void scan1_k(const int* __restrict__ counts,
                                                  int* __restrict__ partial,
                                                  int* __restrict__ blockSums) {
    __shared__ int sm[SCAN_T];
    int tid = threadIdx.x;
    int i = blockIdx.x * SCAN_T + tid;
    int v = (i < NV_C) ? counts[i] : 0;
    int val = v;
    sm[tid] = val;
    __syncthreads();
    for (int off = 1; off < SCAN_T; off <<= 1) {
        int t = (tid >= off) ? sm[tid - off] : 0;
        __syncthreads();
        val += t;
        sm[tid] = val;
        __syncthreads();
    }
    if (i < NV_C) partial[i] = val - v;           // exclusive
    if (tid == SCAN_T - 1) blockSums[blockIdx.x] = val;
}

__global__ void scan2_k(const int* __restrict__ blockSums, int* __restrict__ blockOff) {
    if (blockIdx.x == 0 && threadIdx.x == 0) {
        int run = 0;
        for (int b = 0; b < NB1; ++b) { blockOff[b] = run; run += blockSums[b]; }
    }
}

__global__ void scan3_k(const int* __restrict__ partial, const int* __restrict__ blockOff,
                        int* __restrict__ offsets, int* __restrict__ cursor) {
    int i = blockIdx.x * blockDim.x + threadIdx.x;
    if (i < NV_C) {
        int o = partial[i] + blockOff[i / SCAN_T];
        offsets[i] = o;
        cursor[i]  = o;
    }
    if (i == 0) offsets[NV_C] = NSEL_C;
}

// list[] stores 3*j (float element offset into the batch slice) to save a
// multiply in the gather hot loop.
__global__ void fill_k(const int* __restrict__ vs, int* __restrict__ cursor,
                       int* __restrict__ list) {
    int j = blockIdx.x * blockDim.x + threadIdx.x;
    if (j < NSEL_C) {
        int v = vs[j];
        int pos = atomicAdd(&cursor[v], 1);
        list[pos] = 3 * j;
    }
}

// ---------------- gather (the heavy kernel) ----------------
// 4 vertices per thread: one combined loop over [off[v0], off[v0+4]) with
// predicated accumulation into 12 named registers. Halves wave-level dependent
// iterations (max of Poisson(2.4) vs 4x max of Poisson(0.6)) and makes list[]
// reads sequential per thread. Output: 3x float4 nontemporal stores (12
// floats, 48B-aligned since v0%4==0) -> streaming writes bypass L2, keeping
// the XCD-pinned x slice resident.
// XCD swizzle: batch b only gets wg ids with id%8 == b%8.
__global__ __launch_bounds__(256) void gather4_k(const float* __restrict__ x,
                                                 const int* __restrict__ offsets,
                                                 const int* __restrict__ list,
                                                 float* __restrict__ out) {
    int lin  = blockIdx.x;
    int xcd  = lin & (NXCD - 1);
    int rest = lin >> 3;                 // (b/8)*NBLK_G + t
    int t    = rest % NBLK_G;
    int b    = (rest / NBLK_G) * NXCD + xcd;

    int g = t * 256 + threadIdx.x;       // group of 4 vertices
    if (g >= NGRP) return;
    int v0 = g * 4;

    int o0 = offsets[v0];
    int o1 = offsets[v0 + 1];
    int o2 = offsets[v0 + 2];
    int o3 = offsets[v0 + 3];
    int o4 = offsets[v0 + 4];

    const float* xb = x + (size_t)b * (NSEL_C * 3);

    float f00 = 0.f, f01 = 0.f, f02 = 0.f;
    float f10 = 0.f, f11 = 0.f, f12 = 0.f;
    float f20 = 0.f, f21 = 0.f, f22 = 0.f;
    float f30 = 0.f, f31 = 0.f, f32 = 0.f;

    for (int k = o0; k < o4; ++k) {
        int eo = list[k];                // 3*j
        float p0 = xb[eo];
        float p1 = xb[eo + 1];
        float p2 = xb[eo + 2];
        bool s1 = (k >= o1), s2 = (k >= o2), s3 = (k >= o3);
        bool i0 = !s1;
        bool i1 = s1 && !s2;
        bool i2 = s2 && !s3;
        bool i3 = s3;
        f00 += i0 ? p0 : 0.f;  f01 += i0 ? p1 : 0.f;  f02 += i0 ? p2 : 0.f;
        f10 += i1 ? p0 : 0.f;  f11 += i1 ? p1 : 0.f;  f12 += i1 ? p2 : 0.f;
        f20 += i2 ? p0 : 0.f;  f21 += i2 ? p1 : 0.f;  f22 += i2 ? p2 : 0.f;
        f30 += i3 ? p0 : 0.f;  f31 += i3 ? p1 : 0.f;  f32 += i3 ? p2 : 0.f;
    }

    size_t ob = ((size_t)b * NV_C + v0) * 3;   // byte offset multiple of 48 -> 16B aligned
    f32x4 s0v = {f00, f01, f02, f10};
    f32x4 s1v = {f11, f12, f20, f21};
    f32x4 s2v = {f22, f30, f31, f32};
    __builtin_nontemporal_store(s0v, (f32x4*)(out + ob));
    __builtin_nontemporal_store(s1v, (f32x4*)(out + ob + 4));
    __builtin_nontemporal_store(s2v, (f32x4*)(out + ob + 8));
}

// ---------------- fallback (if ws too small): memset + atomic scatter ----------------
__global__ __launch_bounds__(256) void scatter_atomic_k(const float* __restrict__ x,
                                                        const int* __restrict__ vs,
                                                        float* __restrict__ out) {
    int j = blockIdx.x * blockDim.x + threadIdx.x;
    int b = blockIdx.y;
    if (j < NSEL_C) {
        int v = vs[j];
        const float* p = x + ((size_t)b * NSEL_C + j) * 3;
        float* q = out + ((size_t)b * NV_C + v) * 3;
        atomicAdd(q + 0, p[0]);
        atomicAdd(q + 1, p[1]);
        atomicAdd(q + 2, p[2]);
    }
}

extern "C" void kernel_launch(void* const* d_in, const int* in_sizes, int n_in,
                              void* d_out, int out_size, void* d_ws, size_t ws_size,
                              hipStream_t stream) {
    const float* x  = (const float*)d_in[0];
    const int*   vs = (const int*)d_in[1];
    float* out = (float*)d_out;

    // ws layout (ints): counts[NV] | partial[NV] | offsets[NV+1] | cursor[NV]
    //                   | blockSums[NB1] | blockOff[NB1] | list[NSEL]
    const size_t need_ints = (size_t)4 * NV_C + 1 + 2 * NB1 + NSEL_C;
    if (ws_size >= need_ints * sizeof(int)) {
        int* w        = (int*)d_ws;
        int* counts   = w;
        int* partial  = w + NV_C;
        int* offsets  = w + 2 * NV_C;          // NV_C + 1 entries
        int* cursor   = w + 3 * NV_C + 1;
        int* blockSums= w + 4 * NV_C + 1;
        int* blockOff = blockSums + NB1;
        int* list     = blockOff + NB1;

        zero_counts_k<<<(NV_C + 255) / 256, 256, 0, stream>>>(counts);
        hist_k<<<(NSEL_C + 255) / 256, 256, 0, stream>>>(vs, counts);
        scan1_k<<<NB1, SCAN_T, 0, stream>>>(counts, partial, blockSums);
        scan2_k<<<1, 64, 0, stream>>>(blockSums, blockOff);
        scan3_k<<<(NV_C + 255) / 256, 256, 0, stream>>>(partial, blockOff, offsets, cursor);
        fill_k<<<(NSEL_C + 255) / 256, 256, 0, stream>>>(vs, cursor, list);

        // 1-D swizzled grid: 256 batches x 98 group-blocks (25088 % 8 == 0)
        gather4_k<<<B_C * NBLK_G, 256, 0, stream>>>(x, offsets, list, out);
    } else {
        hipMemsetAsync(d_out, 0, (size_t)out_size * sizeof(float), stream);
        dim3 grid((NSEL_C + 255) / 256, B_C);
        scatter_atomic_k<<<grid, 256, 0, stream>>>(x, vs, out);
    }
}